// Round 10
// baseline (289.200 us; speedup 1.0000x reference)
//
#include <hip/hip_runtime.h>

// RBF kernel: out[i,j] = exp(-||x_i - y_j||^2), x,y: [8192,256] fp32, out fp32.
// dist2 = x2[i] + y2[j] - 2*(x.y); cross term via fp8 e4m3 MFMA, norms fp32.
//
// R9: attack the HBM write path (gemm stores run ~4.2 TB/s vs 6.4 for the
// harness fill). (1) 32x128 tiles: per-store-instruction contiguity 256B ->
// 512B, and the ~128 concurrent blocks/XCD (tx-fastest) tile contiguous
// 64KB column spans of the same 32 rows -> fill-like DRAM page locality.
// (2) nontemporal dwordx4 stores (L2 bypass like the fill). R2's NT failure
// was on scattered 64B dword stores - not applicable to coalesced rows.
// Same single-barrier full-K=256 fp8 MFMA structure, LDS 40KB, 4 blocks/CU.

#define M_DIM 8192
#define K_DIM 256
#define BM 32
#define BN 128
#define TRS 144   // transpose row stride (floats): 128 + 16 (2-way banks max)

typedef long frag8;   // 8 x fp8 in 2 VGPRs
typedef __attribute__((ext_vector_type(4))) float float4v;

// One wave per row: fp32 -> fp8 e4m3 (swizzled) + fp32 sum of squares.
__global__ __launch_bounds__(256) void prep_kernel(
        const float* __restrict__ x, const float* __restrict__ y,
        unsigned char* __restrict__ xb, unsigned char* __restrict__ yb,
        float* __restrict__ x2, float* __restrict__ y2) {
    int row  = blockIdx.x * 4 + (threadIdx.x >> 6);   // 4 waves/block
    int lane = threadIdx.x & 63;

    const float* src; unsigned char* dst; float* nrm; int r;
    if (row < M_DIM) { src = x; dst = xb; nrm = x2; r = row; }
    else             { src = y; dst = yb; nrm = y2; r = row - M_DIM; }

    const float4* s4 = (const float4*)(src + (size_t)r * K_DIM);
    float4 v = s4[lane];
    float ss = v.x * v.x + v.y * v.y + v.z * v.z + v.w * v.w;

    int packed = __builtin_amdgcn_cvt_pk_fp8_f32(v.x, v.y, 0, false);
    packed     = __builtin_amdgcn_cvt_pk_fp8_f32(v.z, v.w, packed, true);

    // XOR-swizzle 16B units within the 256B row: unit u -> u ^ (r&15).
    int u  = lane >> 2;
    int su = u ^ (r & 15);
    *(unsigned int*)(dst + (size_t)r * 256 + su * 16 + (lane & 3) * 4) =
        (unsigned int)packed;

    #pragma unroll
    for (int o = 32; o > 0; o >>= 1) ss += __shfl_down(ss, o);
    if (lane == 0) nrm[r] = ss;
}

// 32x128 tile, 4 waves in 2x2 (each 16x64 = 1x4 MFMA tiles of 16x16x32 fp8).
// Full K=256 staged once, single stage-barrier, LDS-transpose epilogue with
// NT dwordx4 stores. 1D grid of 16384 blocks, XCD-swizzled, tx fastest.
__global__ __launch_bounds__(256, 4) void rbf_gemm(
        const unsigned char* __restrict__ xb, const unsigned char* __restrict__ yb,
        const float* __restrict__ x2, const float* __restrict__ y2,
        float* __restrict__ out) {
    __shared__ __align__(16) unsigned char smem[(BM + BN) * 256];   // 40KB
    unsigned char* As = smem;              // 32 rows x 256B
    unsigned char* Bs = smem + BM * 256;   // 128 rows x 256B
    float* T = (float*)smem;               // 32 x TRS fp32 (18.4KB), reuses As/Bs

    const int tid  = threadIdx.x;
    const int wid  = tid >> 6;
    const int lane = tid & 63;
    const int wm   = wid >> 1;        // 0..1: 16-row half
    const int wn   = wid & 1;         // 0..1: 64-col half

    const int bid = blockIdx.x;
    const int xcd = bid & 7;
    const int lin = bid >> 3;                  // 0..2047 within XCD
    const int ty  = (xcd << 5) + (lin >> 6);   // tile row 0..255
    const int tx  = lin & 63;                  // tile col 0..63 (fastest)
    const int m0  = ty * BM;
    const int n0  = tx * BN;

    // Stage A (8 chunks of 1KB = 4 rows each; 2/wave) + B (32 chunks; 8/wave).
    #pragma unroll
    for (int i = 0; i < 2; ++i) {
        const int ch = wid * 2 + i;
        __builtin_amdgcn_global_load_lds(
            (__attribute__((address_space(1))) void*)
                (xb + (size_t)(m0 + ch * 4) * 256 + lane * 16),
            (__attribute__((address_space(3))) void*)&As[ch * 1024],
            16, 0, 0);
    }
    #pragma unroll
    for (int i = 0; i < 8; ++i) {
        const int ch = wid * 8 + i;
        __builtin_amdgcn_global_load_lds(
            (__attribute__((address_space(1))) void*)
                (yb + (size_t)(n0 + ch * 4) * 256 + lane * 16),
            (__attribute__((address_space(3))) void*)&Bs[ch * 1024],
            16, 0, 0);
    }

    // Hoist norm loads so later barriers have no extra vmem to drain.
    const int q = lane >> 4;          // 0..3
    const int c = lane & 15;
    float x2v[4];
    #pragma unroll
    for (int v = 0; v < 4; ++v)
        x2v[v] = x2[m0 + wm * 16 + q * 4 + v];
    float y2v[4];
    #pragma unroll
    for (int nt = 0; nt < 4; ++nt)
        y2v[nt] = y2[n0 + wn * 64 + nt * 16 + c];

    __syncthreads();   // stage-complete barrier

    const int fr = lane & 15;
    const int g  = lane >> 4;         // 0..3 (k-group of 8 bytes)

    float4v acc[4] = {};

    #pragma unroll
    for (int ks = 0; ks < 8; ++ks) {
        // k-bytes [ks*32 + g*8, +8) live at swizzled unit (2ks+(g>>1))^fr
        // (tile row origins are multiples of 16, so row&15 == fr).
        const int off = (((2 * ks + (g >> 1)) ^ fr) << 4) + (g & 1) * 8;
        const frag8 a = *(const frag8*)&As[(wm * 16 + fr) * 256 + off];
        #pragma unroll
        for (int nt = 0; nt < 4; ++nt) {
            const frag8 b = *(const frag8*)&Bs[(wn * 64 + nt * 16 + fr) * 256 + off];
            acc[nt] = __builtin_amdgcn_mfma_f32_16x16x32_fp8_fp8(
                a, b, acc[nt], 0, 0, 0);
        }
    }

    __syncthreads();   // fragment reads done; As/Bs dead -> reuse as T

    // dist2 = x2 + y2 - 2*s ; r = exp(-max(dist2,0)) (wave-uniform underflow
    // gate: exp(-d)==0.0f exactly for d>=105). Write r into T.
    // C/D layout: col = lane&15, row = q*4 + v.
    #pragma unroll
    for (int nt = 0; nt < 4; ++nt) {
        #pragma unroll
        for (int v = 0; v < 4; ++v) {
            float d = x2v[v] + y2v[nt] - 2.0f * acc[nt][v];
            d = fmaxf(d, 0.0f);
            float r = 0.0f;
            if (__ballot(d < 105.0f) != 0ULL)
                r = (d < 105.0f) ? __expf(-d) : 0.0f;
            T[(wm * 16 + q * 4 + v) * TRS + wn * 64 + nt * 16 + c] = r;
        }
    }

    __syncthreads();   // transpose complete

    // Final store: per instruction 64 lanes x 16B = 2 rows x 512B contiguous;
    // 4 instrs/wave, nontemporal (stream past L2 like the harness fill).
    const int rl = lane >> 5;         // 0..1 row within pair
    const int cl = lane & 31;         // 16B col unit (32 x 16B = 512B)
    #pragma unroll
    for (int i = 0; i < 4; ++i) {
        const int r2 = wid * 8 + i * 2 + rl;
        float4v val = *(const float4v*)&T[r2 * TRS + cl * 4];
        __builtin_nontemporal_store(val,
            (float4v*)&out[(size_t)(m0 + r2) * M_DIM + n0 + cl * 4]);
    }
}

// Fallback if workspace is too small: fp32 tiled direct distance.
__global__ void rbf_naive(const float* __restrict__ x, const float* __restrict__ y,
                          float* __restrict__ out) {
    __shared__ float xs[16][17];
    __shared__ float ys[16][17];
    const int tx = threadIdx.x, ty = threadIdx.y;
    const int row = blockIdx.y * 16 + ty;
    const int col = blockIdx.x * 16 + tx;
    float acc = 0.0f;
    for (int k0 = 0; k0 < K_DIM; k0 += 16) {
        xs[ty][tx] = x[(size_t)row * K_DIM + k0 + tx];
        ys[ty][tx] = y[(size_t)(blockIdx.x * 16 + ty) * K_DIM + k0 + tx];
        __syncthreads();
        #pragma unroll
        for (int kk = 0; kk < 16; ++kk) {
            float d = xs[ty][kk] - ys[tx][kk];
            acc += d * d;
        }
        __syncthreads();
    }
    out[(size_t)row * M_DIM + col] = __expf(-acc);
}

extern "C" void kernel_launch(void* const* d_in, const int* in_sizes, int n_in,
                              void* d_out, int out_size, void* d_ws, size_t ws_size,
                              hipStream_t stream) {
    const float* x = (const float*)d_in[0];
    const float* y = (const float*)d_in[1];
    float* out = (float*)d_out;

    const size_t need = (size_t)2 * M_DIM * 256       // xb, yb (fp8)
                      + (size_t)2 * M_DIM * sizeof(float);
    if (ws_size >= need) {
        unsigned char* xb = (unsigned char*)d_ws;
        unsigned char* yb = xb + (size_t)M_DIM * 256;
        float* x2 = (float*)(yb + (size_t)M_DIM * 256);
        float* y2 = x2 + M_DIM;

        prep_kernel<<<dim3((2 * M_DIM) / 4), dim3(256), 0, stream>>>(x, y, xb, yb, x2, y2);
        rbf_gemm<<<dim3((M_DIM / BM) * (M_DIM / BN)), dim3(256), 0, stream>>>(xb, yb, x2, y2, out);
    } else {
        rbf_naive<<<dim3(M_DIM / 16, M_DIM / 16), dim3(16, 16), 0, stream>>>(x, y, out);
    }
}

// Round 11
// 284.631 us; speedup vs baseline: 1.0161x; 1.0161x over previous
//
#include <hip/hip_runtime.h>

// RBF kernel: out[i,j] = exp(-||x_i - y_j||^2), x,y: [8192,256] fp32, out fp32.
// dist2 = x2[i] + y2[j] - 2*(x.y); cross term via fp8 e4m3 MFMA, norms fp32.
//
// R10: persistent pipelined blocks. R8's 16 rounds/CU each re-paid exposed
// staging latency (stage -> vmcnt(0) barrier with nothing in-block to cover
// it). Now each block owns 8 tiles along tx (fixed ty): A staged ONCE, B
// double-buffered with tile t+1's DMA issued right after tile t's single
// barrier -> a full compute phase in flight, so barriers drain ~nothing.
// Stores from tile t retire during tile t+1. Transpose epilogue dropped
// (R8 proved it perf-neutral): C-layout dword stores, 1 barrier/tile,
// 48KB LDS -> 3 persistent blocks/CU. Staging traffic 512 -> 295 MB.

#define M_DIM 8192
#define K_DIM 256
#define BM 64
#define BN 64
#define TPB 8     // tiles per block (along tx)

typedef long frag8;   // 8 x fp8 in 2 VGPRs
typedef __attribute__((ext_vector_type(4))) float float4v;

// One wave per row: fp32 -> fp8 e4m3 (swizzled) + fp32 sum of squares.
__global__ __launch_bounds__(256) void prep_kernel(
        const float* __restrict__ x, const float* __restrict__ y,
        unsigned char* __restrict__ xb, unsigned char* __restrict__ yb,
        float* __restrict__ x2, float* __restrict__ y2) {
    int row  = blockIdx.x * 4 + (threadIdx.x >> 6);   // 4 waves/block
    int lane = threadIdx.x & 63;

    const float* src; unsigned char* dst; float* nrm; int r;
    if (row < M_DIM) { src = x; dst = xb; nrm = x2; r = row; }
    else             { src = y; dst = yb; nrm = y2; r = row - M_DIM; }

    const float4* s4 = (const float4*)(src + (size_t)r * K_DIM);
    float4 v = s4[lane];
    float ss = v.x * v.x + v.y * v.y + v.z * v.z + v.w * v.w;

    int packed = __builtin_amdgcn_cvt_pk_fp8_f32(v.x, v.y, 0, false);
    packed     = __builtin_amdgcn_cvt_pk_fp8_f32(v.z, v.w, packed, true);

    // XOR-swizzle 16B units within the 256B row: unit u -> u ^ (r&15).
    int u  = lane >> 2;
    int su = u ^ (r & 15);
    *(unsigned int*)(dst + (size_t)r * 256 + su * 16 + (lane & 3) * 4) =
        (unsigned int)packed;

    #pragma unroll
    for (int o = 32; o > 0; o >>= 1) ss += __shfl_down(ss, o);
    if (lane == 0) nrm[r] = ss;
}

// Persistent block: fixed 64-row band (A staged once), 8 consecutive 64-col
// tiles with double-buffered B. 4 waves in 2x2 per tile (each 32x32 = 2x2
// MFMA tiles of 16x16x32 fp8). One barrier per tile. 2048 blocks,
// XCD-swizzled (xcd owns a 16-tile-row band).
__global__ __launch_bounds__(256, 3) void rbf_gemm(
        const unsigned char* __restrict__ xb, const unsigned char* __restrict__ yb,
        const float* __restrict__ x2, const float* __restrict__ y2,
        float* __restrict__ out) {
    __shared__ __align__(16) unsigned char As[BM * 256];        // 16KB
    __shared__ __align__(16) unsigned char Bs[2][BN * 256];     // 2x16KB

    const int tid  = threadIdx.x;
    const int wid  = tid >> 6;
    const int lane = tid & 63;
    const int wm   = wid >> 1;        // 0..1
    const int wn   = wid & 1;         // 0..1

    const int bid = blockIdx.x;
    const int xcd = bid & 7;
    const int lin = bid >> 3;                  // 0..255 within XCD
    const int ty  = (xcd << 4) + (lin >> 4);   // tile row 0..127
    const int tx0 = (lin & 15) * TPB;          // first tile col of this block
    const int m0  = ty * BM;

    // Stage A once: 16 chunks of 1KB (4 rows each), 4 chunks/wave.
    #pragma unroll
    for (int i = 0; i < 4; ++i) {
        const int ch = wid * 4 + i;
        __builtin_amdgcn_global_load_lds(
            (__attribute__((address_space(1))) void*)
                (xb + (size_t)(m0 + ch * 4) * 256 + lane * 16),
            (__attribute__((address_space(3))) void*)&As[ch * 1024],
            16, 0, 0);
    }
    // Stage B(tile 0) into buffer 0.
    #pragma unroll
    for (int i = 0; i < 4; ++i) {
        const int ch = wid * 4 + i;
        __builtin_amdgcn_global_load_lds(
            (__attribute__((address_space(1))) void*)
                (yb + (size_t)(tx0 * BN + ch * 4) * 256 + lane * 16),
            (__attribute__((address_space(3))) void*)&Bs[0][ch * 1024],
            16, 0, 0);
    }

    const int q  = lane >> 4;         // 0..3
    const int c  = lane & 15;
    const int fr = lane & 15;
    const int g  = lane >> 4;         // 0..3 (k-group of 8 bytes)

    // Hoist A-side norms (constant across tiles).
    float x2v[2][4];
    #pragma unroll
    for (int mt = 0; mt < 2; ++mt)
        #pragma unroll
        for (int v = 0; v < 4; ++v)
            x2v[mt][v] = x2[m0 + wm * 32 + mt * 16 + q * 4 + v];

    #pragma unroll 1
    for (int t = 0; t < TPB; ++t) {
        const int cur = t & 1;
        const int n0  = (tx0 + t) * BN;

        __syncthreads();   // drains B(t) DMA (issued ~1 tile ago) + old stores

        // Issue B(t+1) DMA into the other buffer: in flight through this
        // whole tile's compute; drained (for free) at the next barrier.
        if (t + 1 < TPB) {
            #pragma unroll
            for (int i = 0; i < 4; ++i) {
                const int ch = wid * 4 + i;
                __builtin_amdgcn_global_load_lds(
                    (__attribute__((address_space(1))) void*)
                        (yb + (size_t)((n0 + BN) + ch * 4) * 256 + lane * 16),
                    (__attribute__((address_space(3))) void*)&Bs[cur ^ 1][ch * 1024],
                    16, 0, 0);
            }
        }

        float y2v[2];
        #pragma unroll
        for (int nt = 0; nt < 2; ++nt)
            y2v[nt] = y2[n0 + wn * 32 + nt * 16 + c];

        float4v acc[2][2] = {};
        #pragma unroll
        for (int ks = 0; ks < 8; ++ks) {
            // k-bytes [ks*32 + g*8, +8) at swizzled unit (2ks+(g>>1))^fr
            // (tile origins are multiples of 16, so row&15 == fr).
            const int off = (((2 * ks + (g >> 1)) ^ fr) << 4) + (g & 1) * 8;
            frag8 a[2], b[2];
            #pragma unroll
            for (int mt = 0; mt < 2; ++mt)
                a[mt] = *(const frag8*)&As[(wm * 32 + mt * 16 + fr) * 256 + off];
            #pragma unroll
            for (int nt = 0; nt < 2; ++nt)
                b[nt] = *(const frag8*)&Bs[cur][(wn * 32 + nt * 16 + fr) * 256 + off];
            #pragma unroll
            for (int mt = 0; mt < 2; ++mt)
                #pragma unroll
                for (int nt = 0; nt < 2; ++nt)
                    acc[mt][nt] = __builtin_amdgcn_mfma_f32_16x16x32_fp8_fp8(
                        a[mt], b[nt], acc[mt][nt], 0, 0, 0);
        }

        // Epilogue: dist2 = x2 + y2 - 2*s ; r = exp(-max(dist2,0)).
        // C/D layout: col = lane&15, row = q*4 + v. Wave-uniform underflow
        // gate: exp(-d) == 0.0f exactly for d >= 105 in fp32.
        #pragma unroll
        for (int mt = 0; mt < 2; ++mt) {
            const int rowb = m0 + wm * 32 + mt * 16 + q * 4;
            #pragma unroll
            for (int nt = 0; nt < 2; ++nt) {
                const int col = n0 + wn * 32 + nt * 16 + c;
                #pragma unroll
                for (int v = 0; v < 4; ++v) {
                    float d = x2v[mt][v] + y2v[nt] - 2.0f * acc[mt][nt][v];
                    d = fmaxf(d, 0.0f);
                    float r = 0.0f;
                    if (__ballot(d < 105.0f) != 0ULL)
                        r = (d < 105.0f) ? __expf(-d) : 0.0f;
                    out[(size_t)(rowb + v) * M_DIM + col] = r;
                }
            }
        }
        // Stores retire during tile t+1; drained at its barrier.
    }
}

// Fallback if workspace is too small: fp32 tiled direct distance.
__global__ void rbf_naive(const float* __restrict__ x, const float* __restrict__ y,
                          float* __restrict__ out) {
    __shared__ float xs[16][17];
    __shared__ float ys[16][17];
    const int tx = threadIdx.x, ty = threadIdx.y;
    const int row = blockIdx.y * 16 + ty;
    const int col = blockIdx.x * 16 + tx;
    float acc = 0.0f;
    for (int k0 = 0; k0 < K_DIM; k0 += 16) {
        xs[ty][tx] = x[(size_t)row * K_DIM + k0 + tx];
        ys[ty][tx] = y[(size_t)(blockIdx.x * 16 + ty) * K_DIM + k0 + tx];
        __syncthreads();
        #pragma unroll
        for (int kk = 0; kk < 16; ++kk) {
            float d = xs[ty][kk] - ys[tx][kk];
            acc += d * d;
        }
        __syncthreads();
    }
    out[(size_t)row * M_DIM + col] = __expf(-acc);
}

extern "C" void kernel_launch(void* const* d_in, const int* in_sizes, int n_in,
                              void* d_out, int out_size, void* d_ws, size_t ws_size,
                              hipStream_t stream) {
    const float* x = (const float*)d_in[0];
    const float* y = (const float*)d_in[1];
    float* out = (float*)d_out;

    const size_t need = (size_t)2 * M_DIM * 256       // xb, yb (fp8)
                      + (size_t)2 * M_DIM * sizeof(float);
    if (ws_size >= need) {
        unsigned char* xb = (unsigned char*)d_ws;
        unsigned char* yb = xb + (size_t)M_DIM * 256;
        float* x2 = (float*)(yb + (size_t)M_DIM * 256);
        float* y2 = x2 + M_DIM;

        prep_kernel<<<dim3((2 * M_DIM) / 4), dim3(256), 0, stream>>>(x, y, xb, yb, x2, y2);
        const int n_tiles = (M_DIM / BM) * (M_DIM / BN);   // 16384
        rbf_gemm<<<dim3(n_tiles / TPB), dim3(256), 0, stream>>>(xb, yb, x2, y2, out);
    } else {
        rbf_naive<<<dim3(M_DIM / 16, M_DIM / 16), dim3(16, 16), 0, stream>>>(x, y, out);
    }
}